// Round 13
// baseline (265.552 us; speedup 1.0000x reference)
//
#include <hip/hip_runtime.h>
#include <math.h>

typedef unsigned short us;
typedef unsigned long long u64;
typedef short bf16x8 __attribute__((ext_vector_type(8)));
typedef short bf16x4 __attribute__((ext_vector_type(4)));
typedef float f32x4 __attribute__((ext_vector_type(4)));

#define LQ 384
#define DPAIR 128
#define KDIM 12288  // L*32

// ws byte offsets (logits/attn overlap P: P dead after k_qkvg)
#define WT_OFF   0UL
#define P_OFF    262144UL
#define LOG_OFF  262144UL
#define ATT_OFF  2621440UL
#define Q_OFF    38010880UL
#define K_OFF    75759616UL
#define V_OFF    113508352UL
#define G_OFF    151257088UL

__device__ __forceinline__ us f2bf(float x){
  unsigned u = __builtin_bit_cast(unsigned, x);
  return (us)((u + 0x7FFFu + ((u >> 16) & 1u)) >> 16);
}
__device__ __forceinline__ float bf2f(us b){
  unsigned u = ((unsigned)b) << 16;
  return __builtin_bit_cast(float, u);
}
__device__ __forceinline__ void gl_lds16(const void* g, void* l){
  __builtin_amdgcn_global_load_lds((const __attribute__((address_space(1))) unsigned*)g,
                                   (__attribute__((address_space(3))) unsigned*)l, 16, 0, 0);
}
__device__ __forceinline__ void nt_st8(us* p, bf16x8 v){
  __builtin_nontemporal_store(v, (bf16x8*)p);
}
__device__ __forceinline__ float wsum(float x){
  #pragma unroll
  for (int o = 32; o; o >>= 1) x += __shfl_xor(x, o, 64);
  return x;
}
__device__ __forceinline__ float wmaxr(float x){
  #pragma unroll
  for (int o = 32; o; o >>= 1) x = fmaxf(x, __shfl_xor(x, o, 64));
  return x;
}
// stage a 128x64 A/B pair into LDS, pre-swizzled source
__device__ __forceinline__ void stage_pair(const us* __restrict__ Arow, const us* __restrict__ Brow,
                                           size_t strideA, size_t strideB, int koff,
                                           us* ldsA, us* ldsB, int tid)
{
  #pragma unroll
  for (int s = 0; s < 4; ++s) {
    int slot = s * 256 + tid;
    int rrow = slot >> 3, cc = slot & 7;
    int cg = cc ^ (rrow & 7);
    gl_lds16(Arow + (size_t)rrow * strideA + koff + cg * 8, &ldsA[slot * 8]);
    gl_lds16(Brow + (size_t)rrow * strideB + koff + cg * 8, &ldsB[slot * 8]);
  }
}

// ---------------- K0: weight pack (blocks 0..319) + LayerNorm (blocks 320..1471) ----
__global__ __launch_bounds__(256) void k_prep(
    const float* __restrict__ Wq, const float* __restrict__ Wk,
    const float* __restrict__ Wv, const float* __restrict__ Wg,
    const float* __restrict__ Wo, us* __restrict__ wt,
    const float* __restrict__ pair, const float* __restrict__ lng,
    const float* __restrict__ lnb, us* __restrict__ P)
{
  const int bx = blockIdx.x;
  if (bx < 320) {
    int idx = bx * 256 + threadIdx.x;       // < 5*16384
    int m = idx >> 14, rr = idx & 16383, k = rr >> 7, n = rr & 127;
    const float* W; float s;
    switch (m) {
      case 0: W = Wq; s = 0.17677669529663687f; break;   // 1/sqrt(32)
      case 1: W = Wk; s = 0.05103103630798287f; break;   // 1/sqrt(384)
      case 2: W = Wv; s = 1.f; break;
      case 3: W = Wg; s = 1.f; break;
      default: W = Wo; s = 1.f; break;
    }
    wt[m * 16384 + n * 128 + k] = f2bf(W[k * 128 + n] * s);   // WT[n][k]
    return;
  }
  const int tid = threadIdx.x, w = tid >> 6, l = tid & 63;
  const int gw = (bx - 320) * 4 + w;            // 0..4607
  const int b = gw / 12, a0 = (gw % 12) * 32;
  const float2 lg = ((const float2*)lng)[l];
  const float2 lb = ((const float2*)lnb)[l];
  for (int it = 0; it < 8; ++it) {
    float2 x[4];
    #pragma unroll
    for (int rr = 0; rr < 4; ++rr) {
      int a = a0 + it * 4 + rr;
      x[rr] = ((const float2*)(pair + ((size_t)b * LQ + a) * DPAIR))[l];
    }
    #pragma unroll
    for (int rr = 0; rr < 4; ++rr) {
      int a = a0 + it * 4 + rr;
      float s = wsum(x[rr].x + x[rr].y);
      float q = wsum(x[rr].x * x[rr].x + x[rr].y * x[rr].y);
      float mu = s * (1.f / 128.f);
      float var = q * (1.f / 128.f) - mu * mu;
      float rstd = rsqrtf(var + 1e-5f);
      float y0 = (x[rr].x - mu) * rstd * lg.x + lb.x;
      float y1 = (x[rr].y - mu) * rstd * lg.y + lb.y;
      unsigned pk = (unsigned)f2bf(y0) | ((unsigned)f2bf(y1) << 16);
      ((unsigned*)(P + ((size_t)a * LQ + b) * DPAIR))[l] = pk;
    }
  }
}

// ---------------- K1: q/k/v/g projection (R11/v7: QK 4a x 32b, VG 1a x 128b, NT) ----
__global__ __launch_bounds__(256, 4) void k_qkvg(
    const us* __restrict__ P, const us* __restrict__ wt,
    const float* __restrict__ bgp,
    us* __restrict__ Qw, us* __restrict__ Kw, us* __restrict__ Vw, us* __restrict__ Gw)
{
  __shared__ __attribute__((aligned(16))) us lds[17408];   // 34816 B
  const int tid = threadIdx.x, w = tid >> 6, l = tid & 63;
  const int bx = blockIdx.x;
  const int xg = bx & 7, u = bx >> 3;                   // 4608 = 8 XCD * 576
  int type, a_base, b0; bool qk;
  if (u < 288) {          // Q/K: 1152 tiles of (4a x 32b)
    type = u & 1;
    int tq = xg * 144 + (u >> 1);                       // 0..1151
    a_base = (tq / 12) * 4; b0 = (tq % 12) * 32; qk = true;
  } else {                // V/G: 1152 tiles of (1a x 128b)
    int v = u - 288;
    type = 2 + (v & 1);
    int tv = xg * 144 + (v >> 1);
    a_base = tv / 3; b0 = (tv % 3) * 128; qk = false;
  }
  const us* W = wt + type * 16384;
  const int m0 = (w & 1) * 64, n0 = (w >> 1) * 64;
  const int row16 = l & 15, kq = l >> 4;

  // stage full A-tile once, source pre-swizzled
  #pragma unroll
  for (int s = 0; s < 8; ++s) {
    int slot = s * 256 + tid;           // 0..2047
    int r = slot >> 4, c = slot & 15;
    int cg = (c & 8) | ((c & 7) ^ (r & 7));
    size_t prow = qk ? ((size_t)(a_base + (r >> 5)) * LQ + b0 + (r & 31))
                     : ((size_t)a_base * LQ + b0 + r);
    gl_lds16(P + prow * DPAIR + cg * 8, &lds[slot * 8]);
  }
  f32x4 acc[4][4];
  #pragma unroll
  for (int mt = 0; mt < 4; ++mt)
    #pragma unroll
    for (int nt = 0; nt < 4; ++nt) acc[mt][nt] = (f32x4){0.f, 0.f, 0.f, 0.f};
  asm volatile("s_waitcnt vmcnt(0)" ::: "memory");
  __syncthreads();

  #pragma unroll
  for (int kb = 0; kb < 4; ++kb) {
    bf16x8 bv[4], af[4];
    #pragma unroll
    for (int nt = 0; nt < 4; ++nt)
      bv[nt] = *(const bf16x8*)&W[(n0 + nt * 16 + row16) * DPAIR + kb * 32 + kq * 8];
    #pragma unroll
    for (int mt = 0; mt < 4; ++mt) {
      int r = m0 + mt * 16 + row16;
      int c = kb * 4 + kq;
      int cg = (c & 8) | ((c & 7) ^ (r & 7));
      af[mt] = *(const bf16x8*)&lds[r * 128 + cg * 8];
    }
    #pragma unroll
    for (int mt = 0; mt < 4; ++mt)
      #pragma unroll
      for (int nt = 0; nt < 4; ++nt)
        acc[mt][nt] = __builtin_amdgcn_mfma_f32_16x16x32_bf16(af[mt], bv[nt], acc[mt][nt], 0, 0, 0);
  }
  __syncthreads();   // all waves done reading A before overwriting lds

  if (qk) {
    // restage C as T[h*32+bl][ag*32+cc], stride 132 -> 256B-contiguous stores
    us* T = lds;
    #pragma unroll
    for (int nt = 0; nt < 4; ++nt) {
      int n = n0 + nt * 16 + row16, h = n >> 5, cc = n & 31;
      #pragma unroll
      for (int mt = 0; mt < 4; ++mt) {
        f32x4 vv = acc[mt][nt];
        #pragma unroll
        for (int v4 = 0; v4 < 4; ++v4) {
          int r = m0 + mt * 16 + kq * 4 + v4;
          T[(h * 32 + (r & 31)) * 132 + (r >> 5) * 32 + cc] = f2bf(vv[v4]);
        }
      }
    }
    __syncthreads();
    us* dst = (type == 0) ? Qw : Kw;
    #pragma unroll
    for (int it = 0; it < 8; ++it) {
      int slot = it * 256 + tid;       // 0..2047
      int combo = slot >> 4, chunk = slot & 15;
      int h = combo >> 5, bl = combo & 31;
      bf16x8 val = *(const bf16x8*)&T[combo * 132 + chunk * 8];
      nt_st8(&dst[((size_t)h * LQ + b0 + bl) * KDIM + a_base * 32 + chunk * 8], val);
    }
  } else if (type == 2) {
    // V: stage transposed T[col(d) * 132 + row(j)], u32-packed writes
    us* T = lds;
    #pragma unroll
    for (int nt = 0; nt < 4; ++nt) {
      int col = n0 + nt * 16 + row16;
      #pragma unroll
      for (int mt = 0; mt < 4; ++mt) {
        int rowb = m0 + mt * 16 + kq * 4;
        f32x4 vv = acc[mt][nt];
        *(unsigned*)&T[col * 132 + rowb]     = (unsigned)f2bf(vv[0]) | ((unsigned)f2bf(vv[1]) << 16);
        *(unsigned*)&T[col * 132 + rowb + 2] = (unsigned)f2bf(vv[2]) | ((unsigned)f2bf(vv[3]) << 16);
      }
    }
    __syncthreads();
    #pragma unroll
    for (int it = 0; it < 8; ++it) {
      int slot = tid + 256 * it;       // 0..2047
      int d = slot >> 4, jc = slot & 15;
      bf16x4 lo = *(const bf16x4*)&T[d * 132 + jc * 8];
      bf16x4 hi = *(const bf16x4*)&T[d * 132 + jc * 8 + 4];
      bf16x8 val = __builtin_shufflevector(lo, hi, 0, 1, 2, 3, 4, 5, 6, 7);
      int h = d >> 5, dd = d & 31;
      nt_st8(&Vw[((size_t)h * KDIM + a_base * 32 + dd) * LQ + b0 + jc * 8], val);
    }
  } else {
    // G: stage row-major Cs[row * 136 + col], sigmoid fused
    us* Cs = lds;
    #pragma unroll
    for (int nt = 0; nt < 4; ++nt) {
      int col = n0 + nt * 16 + row16;
      float bgv = bgp[col];
      #pragma unroll
      for (int mt = 0; mt < 4; ++mt) {
        f32x4 vv = acc[mt][nt];
        #pragma unroll
        for (int v4 = 0; v4 < 4; ++v4) {
          float e = __expf(-(vv[v4] + bgv));
          Cs[(m0 + mt * 16 + kq * 4 + v4) * 136 + col] = f2bf(1.f / (1.f + e));
        }
      }
    }
    __syncthreads();
    #pragma unroll
    for (int it = 0; it < 8; ++it) {
      int slot = tid + 256 * it;       // 0..2047
      int row = slot >> 4, chunk = slot & 15;
      bf16x8 val = *(const bf16x8*)&Cs[row * 136 + chunk * 8];
      nt_st8(&Gw[((size_t)(a_base * LQ + b0 + row)) * DPAIR + chunk * 8], val);
    }
  }
}

// ---------------- K2: logits += Q K^T (blocks 0..1151, K-split 32) + bias@Wb (1152..2303)
// Both atomicAdd into memset-0 logits -> order-independent.
__global__ __launch_bounds__(256) void k_logits2(
    const us* __restrict__ Qw, const us* __restrict__ Kw,
    const float* __restrict__ bias, const float* __restrict__ Wb,
    float* __restrict__ logits)
{
  __shared__ __attribute__((aligned(16))) us AB[2][2][8192];   // 64 KB dbuf
  const int tid = threadIdx.x, w = tid >> 6, l = tid & 63;
  const int bx = blockIdx.x;
  if (bx >= 1152) {
    // ---- bias projection part ----
    float* bps = (float*)AB;     // [128][5]
    const int u2 = bx - 1152;
    const int i = u2 / 3, j0 = (u2 % 3) * 128;
    const int g = l >> 4, sl = l & 15;
    const float4* Wb4 = (const float4*)Wb;
    float4 wb[8];
    #pragma unroll
    for (int e = 0; e < 8; ++e) wb[e] = Wb4[sl * 8 + e];
    for (int it = 0; it < 8; ++it) {
      int j = j0 + w * 32 + it * 4 + g;
      const float4* br = (const float4*)(bias + ((size_t)i * LQ + j) * DPAIR);
      float4 xa = br[sl * 2], xb = br[sl * 2 + 1];
      float p0 = 0.f, p1 = 0.f, p2 = 0.f, p3 = 0.f;
      #pragma unroll
      for (int e = 0; e < 4; ++e) {
        float xe = ((const float*)&xa)[e];
        p0 += xe * wb[e].x; p1 += xe * wb[e].y; p2 += xe * wb[e].z; p3 += xe * wb[e].w;
        float xf = ((const float*)&xb)[e];
        p0 += xf * wb[4 + e].x; p1 += xf * wb[4 + e].y; p2 += xf * wb[4 + e].z; p3 += xf * wb[4 + e].w;
      }
      #pragma unroll
      for (int o = 1; o < 16; o <<= 1) {
        p0 += __shfl_xor(p0, o, 64);
        p1 += __shfl_xor(p1, o, 64);
        p2 += __shfl_xor(p2, o, 64);
        p3 += __shfl_xor(p3, o, 64);
      }
      if (sl == 0) {
        int row = w * 32 + it * 4 + g;
        bps[row * 5 + 0] = p0; bps[row * 5 + 1] = p1; bps[row * 5 + 2] = p2; bps[row * 5 + 3] = p3;
      }
    }
    __syncthreads();
    #pragma unroll
    for (int rep = 0; rep < 2; ++rep) {
      int slot = rep * 256 + tid;               // 0..511
      int h = slot >> 7, jj = slot & 127;
      atomicAdd(&logits[((size_t)h * LQ + i) * LQ + j0 + jj], bps[jj * 5 + h]);
    }
    return;
  }
  // ---- QK^T GEMM part (K-split 32, dbuf counted-vmcnt, 6 rounds) ----
  const int xg = bx & 7, yg = bx >> 3;        // 1152 blocks: yg 0..143
  const int set = xg * 48 + yg / 3, j0 = (yg % 3) * 128;
  const int h = set / 96, rem = set % 96, i0 = (rem / 32) * 128, ks = rem % 32;
  const us* Ab = Qw + (size_t)h * LQ * KDIM + (size_t)i0 * KDIM;
  const us* Bb = Kw + (size_t)h * LQ * KDIM + (size_t)j0 * KDIM;
  f32x4 acc[4][4];
  #pragma unroll
  for (int mt = 0; mt < 4; ++mt)
    #pragma unroll
    for (int nt = 0; nt < 4; ++nt) acc[mt][nt] = (f32x4){0.f, 0.f, 0.f, 0.f};
  const int m0 = (w & 1) * 64, n0 = (w >> 1) * 64;
  const int row16 = l & 15, kq = l >> 4;
  stage_pair(Ab, Bb, KDIM, KDIM, ks * 384, AB[0][0], AB[0][1], tid);
  for (int kk = 0; kk < 6; ++kk) {
    const int cur = kk & 1;
    if (kk < 5) {
      stage_pair(Ab, Bb, KDIM, KDIM, ks * 384 + (kk + 1) * 64, AB[cur ^ 1][0], AB[cur ^ 1][1], tid);
      asm volatile("s_waitcnt vmcnt(8)" ::: "memory");
    } else {
      asm volatile("s_waitcnt vmcnt(0)" ::: "memory");
    }
    __syncthreads();
    #pragma unroll
    for (int kb = 0; kb < 2; ++kb) {
      bf16x8 af[4], bv[4];
      #pragma unroll
      for (int mt = 0; mt < 4; ++mt) {
        int r = m0 + mt * 16 + row16;
        int c = (kb * 4 + kq) ^ (r & 7);
        af[mt] = *(const bf16x8*)&AB[cur][0][r * 64 + c * 8];
      }
      #pragma unroll
      for (int nt = 0; nt < 4; ++nt) {
        int r = n0 + nt * 16 + row16;
        int c = (kb * 4 + kq) ^ (r & 7);
        bv[nt] = *(const bf16x8*)&AB[cur][1][r * 64 + c * 8];
      }
      #pragma unroll
      for (int mt = 0; mt < 4; ++mt)
        #pragma unroll
        for (int nt = 0; nt < 4; ++nt)
          acc[mt][nt] = __builtin_amdgcn_mfma_f32_16x16x32_bf16(af[mt], bv[nt], acc[mt][nt], 0, 0, 0);
    }
    __syncthreads();
  }
  #pragma unroll
  for (int mt = 0; mt < 4; ++mt)
    #pragma unroll
    for (int nt = 0; nt < 4; ++nt)
      #pragma unroll
      for (int v4 = 0; v4 < 4; ++v4) {
        int i = i0 + m0 + mt * 16 + kq * 4 + v4;
        int j = j0 + n0 + nt * 16 + row16;
        atomicAdd(&logits[((size_t)h * LQ + i) * LQ + j], acc[mt][nt][v4]);
      }
}

// ---------------- K3: softmax over j ----------------
__global__ __launch_bounds__(256) void k_softmax(
    const float* __restrict__ logits, us* __restrict__ attn)
{
  const int tid = threadIdx.x, h = tid >> 6, l = tid & 63;
  const int i = blockIdx.x;
  const float* lrow = logits + ((size_t)h * LQ + i) * LQ;
  float x[6];
  #pragma unroll
  for (int s = 0; s < 6; ++s) x[s] = lrow[l + 64 * s];
  float mx = x[0];
  #pragma unroll
  for (int s = 1; s < 6; ++s) mx = fmaxf(mx, x[s]);
  mx = wmaxr(mx);
  float e[6], sum = 0.f;
  #pragma unroll
  for (int s = 0; s < 6; ++s) { e[s] = expf(x[s] - mx); sum += e[s]; }
  sum = wsum(sum);
  float rinv = 1.f / sum;
  #pragma unroll
  for (int s = 0; s < 6; ++s)
    attn[((size_t)h * LQ + i) * LQ + l + 64 * s] = f2bf(e[s] * rinv);
}

// ---------------- K4: o = attn @ V^T (dbuf), fused gating, E over G ----------------
__global__ __launch_bounds__(256) void k_ogemm(
    const us* __restrict__ attn, const us* __restrict__ Vw, us* __restrict__ Gw)
{
  __shared__ __attribute__((aligned(16))) us AB[2][2][8192];   // 64 KB dbuf
  const int tid = threadIdx.x, w = tid >> 6, l = tid & 63;
  const int bx = blockIdx.x;
  const int xg = bx & 7, yg = bx >> 3;        // 1152 blocks
  const int set = xg * 48 + yg / 3, i0 = (yg % 3) * 128;
  const int h = set / 96, n0 = (set % 96) * 128;
  const us* Ab = attn + (size_t)h * LQ * LQ + (size_t)i0 * LQ;
  const us* Bb = Vw + (size_t)h * KDIM * LQ + (size_t)n0 * LQ;
  f32x4 acc[4][4];
  #pragma unroll
  for (int mt = 0; mt < 4; ++mt)
    #pragma unroll
    for (int nt = 0; nt < 4; ++nt) acc[mt][nt] = (f32x4){0.f, 0.f, 0.f, 0.f};
  const int m0 = (w & 1) * 64, n0w = (w >> 1) * 64;
  const int row16 = l & 15, kq = l >> 4;
  stage_pair(Ab, Bb, LQ, LQ, 0, AB[0][0], AB[0][1], tid);
  for (int kk = 0; kk < 6; ++kk) {
    const int cur = kk & 1;
    if (kk < 5) {
      stage_pair(Ab, Bb, LQ, LQ, (kk + 1) * 64, AB[cur ^ 1][0], AB[cur ^ 1][1], tid);
      asm volatile("s_waitcnt vmcnt(8)" ::: "memory");
    } else {
      asm volatile("s_waitcnt vmcnt(0)" ::: "memory");
    }
    __syncthreads();
    #pragma unroll
    for (int kb = 0; kb < 2; ++kb) {
      bf16x8 af[4], bv[4];
      #pragma unroll
      for (int mt = 0; mt < 4; ++mt) {
        int r = m0 + mt * 16 + row16;
        int c = (kb * 4 + kq) ^ (r & 7);
        af[mt] = *(const bf16x8*)&AB[cur][0][r * 64 + c * 8];
      }
      #pragma unroll
      for (int nt = 0; nt < 4; ++nt) {
        int r = n0w + nt * 16 + row16;
        int c = (kb * 4 + kq) ^ (r & 7);
        bv[nt] = *(const bf16x8*)&AB[cur][1][r * 64 + c * 8];
      }
      #pragma unroll
      for (int mt = 0; mt < 4; ++mt)
        #pragma unroll
        for (int nt = 0; nt < 4; ++nt)
          acc[mt][nt] = __builtin_amdgcn_mfma_f32_16x16x32_bf16(af[mt], bv[nt], acc[mt][nt], 0, 0, 0);
    }
    __syncthreads();
  }
  // stage C (128x128 bf16 over buf0)
  us* C = (us*)AB;
  #pragma unroll
  for (int mt = 0; mt < 4; ++mt)
    #pragma unroll
    for (int nt = 0; nt < 4; ++nt)
      #pragma unroll
      for (int v4 = 0; v4 < 4; ++v4)
        C[(m0 + mt * 16 + kq * 4 + v4) * 128 + n0w + nt * 16 + row16] = f2bf(acc[mt][nt][v4]);
  __syncthreads();
  // gated store: E[(i*384 + k)*128 + h*32 + d] = g * o, in-place over Gw
  const int k0 = n0 >> 5;
  #pragma unroll
  for (int it = 0; it < 8; ++it) {
    int slot = tid + 256 * it;      // 0..2047
    int xr = slot >> 4, ch = slot & 15;
    bf16x8 ov = *(const bf16x8*)&C[xr * 128 + ch * 8];
    size_t eaddr = ((size_t)(i0 + xr) * LQ + k0 + (ch >> 2)) * DPAIR + h * 32 + (ch & 3) * 8;
    bf16x8 gv = *(const bf16x8*)&Gw[eaddr];
    bf16x8 ev;
    #pragma unroll
    for (int q = 0; q < 8; ++q)
      ev[q] = (short)f2bf(bf2f((us)(unsigned short)ov[q]) * bf2f((us)(unsigned short)gv[q]));
    *(bf16x8*)&Gw[eaddr] = ev;
  }
}

// ---------------- K5: out[y,x,:] = E[x,y,:] @ Wo + bo (fp32 restage + NT out) ------
__global__ __launch_bounds__(256) void k_final(
    const us* __restrict__ E, const us* __restrict__ wt,
    const float* __restrict__ bo, float* __restrict__ out)
{
  __shared__ __attribute__((aligned(16))) us A[17408];    // 34816 B
  const int tid = threadIdx.x, w = tid >> 6, l = tid & 63;
  const int y = blockIdx.x / 3, x0 = (blockIdx.x % 3) * 128;
  #pragma unroll
  for (int s4 = 0; s4 < 8; ++s4) {
    int slot = s4 * 256 + tid;
    int r = slot >> 4, c = slot & 15;
    int cg = (c & 8) | ((c & 7) ^ (r & 7));
    gl_lds16(E + ((size_t)(x0 + r) * LQ + y) * DPAIR + cg * 8, &A[slot * 8]);
  }
  asm volatile("s_waitcnt vmcnt(0)" ::: "memory");
  __syncthreads();
  const us* W = wt + 4 * 16384;       // WoT
  const int m0 = (w & 1) * 64, n0w = (w >> 1) * 64;
  const int row16 = l & 15, kq = l >> 4;
  f32x4 acc[4][4];
  #pragma unroll
  for (int mt = 0; mt < 4; ++mt)
    #pragma unroll
    for (int nt = 0; nt < 4; ++nt) acc[mt][nt] = (f32x4){0.f, 0.f, 0.f, 0.f};
  #pragma unroll
  for (int kb = 0; kb < 4; ++kb) {
    bf16x8 af[4], bv[4];
    #pragma unroll
    for (int mt = 0; mt < 4; ++mt) {
      int r = m0 + mt * 16 + row16;
      int c = (kb * 4 + kq);
      int cg = (c & 8) | ((c & 7) ^ (r & 7));
      af[mt] = *(const bf16x8*)&A[r * 128 + cg * 8];
    }
    #pragma unroll
    for (int nt = 0; nt < 4; ++nt)
      bv[nt] = *(const bf16x8*)&W[(n0w + nt * 16 + row16) * 128 + kb * 32 + kq * 8];
    #pragma unroll
    for (int mt = 0; mt < 4; ++mt)
      #pragma unroll
      for (int nt = 0; nt < 4; ++nt)
        acc[mt][nt] = __builtin_amdgcn_mfma_f32_16x16x32_bf16(af[mt], bv[nt], acc[mt][nt], 0, 0, 0);
  }
  __syncthreads();   // A dead; reuse as fp32 stage [64][136]
  float* Sf = (float*)A;
  #pragma unroll
  for (int half = 0; half < 2; ++half) {
    if ((w & 1) == half) {
      #pragma unroll
      for (int nt = 0; nt < 4; ++nt) {
        int col = n0w + nt * 16 + row16;
        float bov = bo[col];
        #pragma unroll
        for (int mt = 0; mt < 4; ++mt) {
          f32x4 vv = acc[mt][nt];
          #pragma unroll
          for (int v4 = 0; v4 < 4; ++v4)
            Sf[(mt * 16 + kq * 4 + v4) * 136 + col] = vv[v4] + bov;
        }
      }
    }
    __syncthreads();
    #pragma unroll
    for (int it = 0; it < 8; ++it) {
      int slot = it * 256 + tid;        // 0..2047
      int rw = slot >> 5, ch = slot & 31;
      f32x4 v = *(const f32x4*)&Sf[rw * 136 + ch * 4];
      __builtin_nontemporal_store(v,
        (f32x4*)&out[((size_t)y * LQ + x0 + half * 64 + rw) * DPAIR + ch * 4]);
    }
    __syncthreads();
  }
}

extern "C" void kernel_launch(void* const* d_in, const int* in_sizes, int n_in,
                              void* d_out, int out_size, void* d_ws, size_t ws_size,
                              hipStream_t stream)
{
  const float* pair = (const float*)d_in[0];
  const float* bias = (const float*)d_in[1];
  const float* lng  = (const float*)d_in[2];
  const float* lnb  = (const float*)d_in[3];
  const float* Wq   = (const float*)d_in[4];
  const float* Wk   = (const float*)d_in[5];
  const float* Wv   = (const float*)d_in[6];
  const float* Wb   = (const float*)d_in[7];
  const float* Wg   = (const float*)d_in[8];
  const float* bg   = (const float*)d_in[9];
  const float* Wo   = (const float*)d_in[10];
  const float* bo   = (const float*)d_in[11];

  char* ws = (char*)d_ws;
  us* wt     = (us*)(ws + WT_OFF);
  us* P      = (us*)(ws + P_OFF);
  us* Qw     = (us*)(ws + Q_OFF);
  us* Kw     = (us*)(ws + K_OFF);
  us* Vw     = (us*)(ws + V_OFF);
  us* Gw     = (us*)(ws + G_OFF);
  us* attn   = (us*)(ws + ATT_OFF);
  float* logits = (float*)(ws + LOG_OFF);

  k_prep<<<1472, 256, 0, stream>>>(Wq, Wk, Wv, Wg, Wo, wt, pair, lng, lnb, P);
  k_qkvg<<<4608, 256, 0, stream>>>(P, wt, bg, Qw, Kw, Vw, Gw);
  // P dead from here; logits/attn overlap its region
  (void)hipMemsetAsync(logits, 0, (size_t)4 * LQ * LQ * 4, stream);
  k_logits2<<<2304, 256, 0, stream>>>(Qw, Kw, bias, Wb, logits);
  k_softmax<<<384, 256, 0, stream>>>(logits, attn);
  k_ogemm<<<1152, 256, 0, stream>>>(attn, Vw, Gw);
  k_final<<<1152, 256, 0, stream>>>(Gw, wt, bo, (float*)d_out);
}

// Round 14
// 241.018 us; speedup vs baseline: 1.1018x; 1.1018x over previous
//
#include <hip/hip_runtime.h>
#include <math.h>

typedef unsigned short us;
typedef unsigned long long u64;
typedef short bf16x8 __attribute__((ext_vector_type(8)));
typedef short bf16x4 __attribute__((ext_vector_type(4)));
typedef float f32x4 __attribute__((ext_vector_type(4)));

#define LQ 384
#define DPAIR 128
#define KDIM 12288  // L*32

// ws byte offsets (logits/attn overlap P: P dead after k_qkvg)
#define WT_OFF   0UL
#define P_OFF    262144UL
#define LOG_OFF  262144UL
#define ATT_OFF  2621440UL
#define Q_OFF    38010880UL
#define K_OFF    75759616UL
#define V_OFF    113508352UL
#define G_OFF    151257088UL

__device__ __forceinline__ us f2bf(float x){
  unsigned u = __builtin_bit_cast(unsigned, x);
  return (us)((u + 0x7FFFu + ((u >> 16) & 1u)) >> 16);
}
__device__ __forceinline__ float bf2f(us b){
  unsigned u = ((unsigned)b) << 16;
  return __builtin_bit_cast(float, u);
}
__device__ __forceinline__ void gl_lds16(const void* g, void* l){
  __builtin_amdgcn_global_load_lds((const __attribute__((address_space(1))) unsigned*)g,
                                   (__attribute__((address_space(3))) unsigned*)l, 16, 0, 0);
}
__device__ __forceinline__ void nt_st8(us* p, bf16x8 v){
  __builtin_nontemporal_store(v, (bf16x8*)p);
}
__device__ __forceinline__ float wsum(float x){
  #pragma unroll
  for (int o = 32; o; o >>= 1) x += __shfl_xor(x, o, 64);
  return x;
}
__device__ __forceinline__ float wmaxr(float x){
  #pragma unroll
  for (int o = 32; o; o >>= 1) x = fmaxf(x, __shfl_xor(x, o, 64));
  return x;
}
// stage a 128x64 A/B pair into LDS, pre-swizzled source (256-thread blocks)
__device__ __forceinline__ void stage_pair(const us* __restrict__ Arow, const us* __restrict__ Brow,
                                           size_t strideA, size_t strideB, int koff,
                                           us* ldsA, us* ldsB, int tid)
{
  #pragma unroll
  for (int s = 0; s < 4; ++s) {
    int slot = s * 256 + tid;
    int rrow = slot >> 3, cc = slot & 7;
    int cg = cc ^ (rrow & 7);
    gl_lds16(Arow + (size_t)rrow * strideA + koff + cg * 8, &ldsA[slot * 8]);
    gl_lds16(Brow + (size_t)rrow * strideB + koff + cg * 8, &ldsB[slot * 8]);
  }
}
// same but for 512-thread blocks (2 iterations)
__device__ __forceinline__ void stage_pair512(const us* __restrict__ Arow, const us* __restrict__ Brow,
                                              size_t strideA, size_t strideB, int koff,
                                              us* ldsA, us* ldsB, int tid)
{
  #pragma unroll
  for (int s = 0; s < 2; ++s) {
    int slot = s * 512 + tid;
    int rrow = slot >> 3, cc = slot & 7;
    int cg = cc ^ (rrow & 7);
    gl_lds16(Arow + (size_t)rrow * strideA + koff + cg * 8, &ldsA[slot * 8]);
    gl_lds16(Brow + (size_t)rrow * strideB + koff + cg * 8, &ldsB[slot * 8]);
  }
}

// ---------------- K0: weight pack (blocks 0..319) + LayerNorm (blocks 320..1471) ----
__global__ __launch_bounds__(256) void k_prep(
    const float* __restrict__ Wq, const float* __restrict__ Wk,
    const float* __restrict__ Wv, const float* __restrict__ Wg,
    const float* __restrict__ Wo, us* __restrict__ wt,
    const float* __restrict__ pair, const float* __restrict__ lng,
    const float* __restrict__ lnb, us* __restrict__ P)
{
  const int bx = blockIdx.x;
  if (bx < 320) {
    int idx = bx * 256 + threadIdx.x;       // < 5*16384
    int m = idx >> 14, rr = idx & 16383, k = rr >> 7, n = rr & 127;
    const float* W; float s;
    switch (m) {
      case 0: W = Wq; s = 0.17677669529663687f; break;   // 1/sqrt(32)
      case 1: W = Wk; s = 0.05103103630798287f; break;   // 1/sqrt(384)
      case 2: W = Wv; s = 1.f; break;
      case 3: W = Wg; s = 1.f; break;
      default: W = Wo; s = 1.f; break;
    }
    wt[m * 16384 + n * 128 + k] = f2bf(W[k * 128 + n] * s);   // WT[n][k]
    return;
  }
  const int tid = threadIdx.x, w = tid >> 6, l = tid & 63;
  const int gw = (bx - 320) * 4 + w;            // 0..4607
  const int b = gw / 12, a0 = (gw % 12) * 32;
  const float2 lg = ((const float2*)lng)[l];
  const float2 lb = ((const float2*)lnb)[l];
  for (int it = 0; it < 8; ++it) {
    float2 x[4];
    #pragma unroll
    for (int rr = 0; rr < 4; ++rr) {
      int a = a0 + it * 4 + rr;
      x[rr] = ((const float2*)(pair + ((size_t)b * LQ + a) * DPAIR))[l];
    }
    #pragma unroll
    for (int rr = 0; rr < 4; ++rr) {
      int a = a0 + it * 4 + rr;
      float s = wsum(x[rr].x + x[rr].y);
      float q = wsum(x[rr].x * x[rr].x + x[rr].y * x[rr].y);
      float mu = s * (1.f / 128.f);
      float var = q * (1.f / 128.f) - mu * mu;
      float rstd = rsqrtf(var + 1e-5f);
      float y0 = (x[rr].x - mu) * rstd * lg.x + lb.x;
      float y1 = (x[rr].y - mu) * rstd * lg.y + lb.y;
      unsigned pk = (unsigned)f2bf(y0) | ((unsigned)f2bf(y1) << 16);
      ((unsigned*)(P + ((size_t)a * LQ + b) * DPAIR))[l] = pk;
    }
  }
}

// ---------------- K1: q/k/v/g projection (R11/v7: QK 4a x 32b, VG 1a x 128b, NT) ----
__global__ __launch_bounds__(256, 4) void k_qkvg(
    const us* __restrict__ P, const us* __restrict__ wt,
    const float* __restrict__ bgp,
    us* __restrict__ Qw, us* __restrict__ Kw, us* __restrict__ Vw, us* __restrict__ Gw)
{
  __shared__ __attribute__((aligned(16))) us lds[17408];   // 34816 B
  const int tid = threadIdx.x, w = tid >> 6, l = tid & 63;
  const int bx = blockIdx.x;
  const int xg = bx & 7, u = bx >> 3;                   // 4608 = 8 XCD * 576
  int type, a_base, b0; bool qk;
  if (u < 288) {          // Q/K: 1152 tiles of (4a x 32b)
    type = u & 1;
    int tq = xg * 144 + (u >> 1);                       // 0..1151
    a_base = (tq / 12) * 4; b0 = (tq % 12) * 32; qk = true;
  } else {                // V/G: 1152 tiles of (1a x 128b)
    int v = u - 288;
    type = 2 + (v & 1);
    int tv = xg * 144 + (v >> 1);
    a_base = tv / 3; b0 = (tv % 3) * 128; qk = false;
  }
  const us* W = wt + type * 16384;
  const int m0 = (w & 1) * 64, n0 = (w >> 1) * 64;
  const int row16 = l & 15, kq = l >> 4;

  // stage full A-tile once, source pre-swizzled
  #pragma unroll
  for (int s = 0; s < 8; ++s) {
    int slot = s * 256 + tid;           // 0..2047
    int r = slot >> 4, c = slot & 15;
    int cg = (c & 8) | ((c & 7) ^ (r & 7));
    size_t prow = qk ? ((size_t)(a_base + (r >> 5)) * LQ + b0 + (r & 31))
                     : ((size_t)a_base * LQ + b0 + r);
    gl_lds16(P + prow * DPAIR + cg * 8, &lds[slot * 8]);
  }
  f32x4 acc[4][4];
  #pragma unroll
  for (int mt = 0; mt < 4; ++mt)
    #pragma unroll
    for (int nt = 0; nt < 4; ++nt) acc[mt][nt] = (f32x4){0.f, 0.f, 0.f, 0.f};
  asm volatile("s_waitcnt vmcnt(0)" ::: "memory");
  __syncthreads();

  #pragma unroll
  for (int kb = 0; kb < 4; ++kb) {
    bf16x8 bv[4], af[4];
    #pragma unroll
    for (int nt = 0; nt < 4; ++nt)
      bv[nt] = *(const bf16x8*)&W[(n0 + nt * 16 + row16) * DPAIR + kb * 32 + kq * 8];
    #pragma unroll
    for (int mt = 0; mt < 4; ++mt) {
      int r = m0 + mt * 16 + row16;
      int c = kb * 4 + kq;
      int cg = (c & 8) | ((c & 7) ^ (r & 7));
      af[mt] = *(const bf16x8*)&lds[r * 128 + cg * 8];
    }
    #pragma unroll
    for (int mt = 0; mt < 4; ++mt)
      #pragma unroll
      for (int nt = 0; nt < 4; ++nt)
        acc[mt][nt] = __builtin_amdgcn_mfma_f32_16x16x32_bf16(af[mt], bv[nt], acc[mt][nt], 0, 0, 0);
  }
  __syncthreads();   // all waves done reading A before overwriting lds

  if (qk) {
    // restage C as T[h*32+bl][ag*32+cc], stride 132 -> 256B-contiguous stores
    us* T = lds;
    #pragma unroll
    for (int nt = 0; nt < 4; ++nt) {
      int n = n0 + nt * 16 + row16, h = n >> 5, cc = n & 31;
      #pragma unroll
      for (int mt = 0; mt < 4; ++mt) {
        f32x4 vv = acc[mt][nt];
        #pragma unroll
        for (int v4 = 0; v4 < 4; ++v4) {
          int r = m0 + mt * 16 + kq * 4 + v4;
          T[(h * 32 + (r & 31)) * 132 + (r >> 5) * 32 + cc] = f2bf(vv[v4]);
        }
      }
    }
    __syncthreads();
    us* dst = (type == 0) ? Qw : Kw;
    #pragma unroll
    for (int it = 0; it < 8; ++it) {
      int slot = it * 256 + tid;       // 0..2047
      int combo = slot >> 4, chunk = slot & 15;
      int h = combo >> 5, bl = combo & 31;
      bf16x8 val = *(const bf16x8*)&T[combo * 132 + chunk * 8];
      nt_st8(&dst[((size_t)h * LQ + b0 + bl) * KDIM + a_base * 32 + chunk * 8], val);
    }
  } else if (type == 2) {
    // V: stage transposed T[col(d) * 132 + row(j)], u32-packed writes
    us* T = lds;
    #pragma unroll
    for (int nt = 0; nt < 4; ++nt) {
      int col = n0 + nt * 16 + row16;
      #pragma unroll
      for (int mt = 0; mt < 4; ++mt) {
        int rowb = m0 + mt * 16 + kq * 4;
        f32x4 vv = acc[mt][nt];
        *(unsigned*)&T[col * 132 + rowb]     = (unsigned)f2bf(vv[0]) | ((unsigned)f2bf(vv[1]) << 16);
        *(unsigned*)&T[col * 132 + rowb + 2] = (unsigned)f2bf(vv[2]) | ((unsigned)f2bf(vv[3]) << 16);
      }
    }
    __syncthreads();
    #pragma unroll
    for (int it = 0; it < 8; ++it) {
      int slot = tid + 256 * it;       // 0..2047
      int d = slot >> 4, jc = slot & 15;
      bf16x4 lo = *(const bf16x4*)&T[d * 132 + jc * 8];
      bf16x4 hi = *(const bf16x4*)&T[d * 132 + jc * 8 + 4];
      bf16x8 val = __builtin_shufflevector(lo, hi, 0, 1, 2, 3, 4, 5, 6, 7);
      int h = d >> 5, dd = d & 31;
      nt_st8(&Vw[((size_t)h * KDIM + a_base * 32 + dd) * LQ + b0 + jc * 8], val);
    }
  } else {
    // G: stage row-major Cs[row * 136 + col], sigmoid fused
    us* Cs = lds;
    #pragma unroll
    for (int nt = 0; nt < 4; ++nt) {
      int col = n0 + nt * 16 + row16;
      float bgv = bgp[col];
      #pragma unroll
      for (int mt = 0; mt < 4; ++mt) {
        f32x4 vv = acc[mt][nt];
        #pragma unroll
        for (int v4 = 0; v4 < 4; ++v4) {
          float e = __expf(-(vv[v4] + bgv));
          Cs[(m0 + mt * 16 + kq * 4 + v4) * 136 + col] = f2bf(1.f / (1.f + e));
        }
      }
    }
    __syncthreads();
    #pragma unroll
    for (int it = 0; it < 8; ++it) {
      int slot = tid + 256 * it;       // 0..2047
      int row = slot >> 4, chunk = slot & 15;
      bf16x8 val = *(const bf16x8*)&Cs[row * 136 + chunk * 8];
      nt_st8(&Gw[((size_t)(a_base * LQ + b0 + row)) * DPAIR + chunk * 8], val);
    }
  }
}

// ---------------- K2: 512-thread: logits += Q K^T (blocks 0..575) + bias@Wb (576..1727)
// Both atomicAdd into memset-0 logits -> order-independent. 8 waves/block ->
// 16 waves/CU at 2 blocks/CU (double R11's latency-hiding).
__global__ __launch_bounds__(512) void k_logits2(
    const us* __restrict__ Qw, const us* __restrict__ Kw,
    const float* __restrict__ bias, const float* __restrict__ Wb,
    float* __restrict__ logits)
{
  __shared__ __attribute__((aligned(16))) us AB[2][2][8192];   // 64 KB dbuf
  const int tid = threadIdx.x, w = tid >> 6, l = tid & 63;
  const int bx = blockIdx.x;
  if (bx >= 576) {
    // ---- bias projection part (8 waves x 4 rows x 4 iters = 128 j-rows) ----
    float* bps = (float*)AB;     // [128][5]
    const int u2 = bx - 576;
    const int i = u2 / 3, j0 = (u2 % 3) * 128;
    const int g = l >> 4, sl = l & 15;
    const float4* Wb4 = (const float4*)Wb;
    float4 wb[8];
    #pragma unroll
    for (int e = 0; e < 8; ++e) wb[e] = Wb4[sl * 8 + e];
    #pragma unroll
    for (int it = 0; it < 4; ++it) {
      int row = it * 32 + w * 4 + g;
      int j = j0 + row;
      const float4* br = (const float4*)(bias + ((size_t)i * LQ + j) * DPAIR);
      float4 xa = br[sl * 2], xb = br[sl * 2 + 1];
      float p0 = 0.f, p1 = 0.f, p2 = 0.f, p3 = 0.f;
      #pragma unroll
      for (int e = 0; e < 4; ++e) {
        float xe = ((const float*)&xa)[e];
        p0 += xe * wb[e].x; p1 += xe * wb[e].y; p2 += xe * wb[e].z; p3 += xe * wb[e].w;
        float xf = ((const float*)&xb)[e];
        p0 += xf * wb[4 + e].x; p1 += xf * wb[4 + e].y; p2 += xf * wb[4 + e].z; p3 += xf * wb[4 + e].w;
      }
      #pragma unroll
      for (int o = 1; o < 16; o <<= 1) {
        p0 += __shfl_xor(p0, o, 64);
        p1 += __shfl_xor(p1, o, 64);
        p2 += __shfl_xor(p2, o, 64);
        p3 += __shfl_xor(p3, o, 64);
      }
      if (sl == 0) {
        bps[row * 5 + 0] = p0; bps[row * 5 + 1] = p1; bps[row * 5 + 2] = p2; bps[row * 5 + 3] = p3;
      }
    }
    __syncthreads();
    {
      int h = tid >> 7, jj = tid & 127;
      atomicAdd(&logits[((size_t)h * LQ + i) * LQ + j0 + jj], bps[jj * 5 + h]);
    }
    return;
  }
  // ---- QK^T GEMM (K-split 16, dbuf counted-vmcnt, 8 waves 2x4) ----
  const int xg = bx & 7, yg = bx >> 3;        // 576 blocks: yg 0..71
  const int set = xg * 24 + yg / 3, j0 = (yg % 3) * 128;
  const int h = set / 48, rem = set % 48, i0 = (rem / 16) * 128, ks = rem % 16;
  const us* Ab = Qw + (size_t)h * LQ * KDIM + (size_t)i0 * KDIM;
  const us* Bb = Kw + (size_t)h * LQ * KDIM + (size_t)j0 * KDIM;
  f32x4 acc[4][2];
  #pragma unroll
  for (int mt = 0; mt < 4; ++mt) { acc[mt][0] = (f32x4){0,0,0,0}; acc[mt][1] = (f32x4){0,0,0,0}; }
  const int m0 = (w & 1) * 64, n0 = (w >> 1) * 32;
  const int row16 = l & 15, kq = l >> 4;
  stage_pair512(Ab, Bb, KDIM, KDIM, ks * 768, AB[0][0], AB[0][1], tid);
  for (int kk = 0; kk < 12; ++kk) {
    const int cur = kk & 1;
    if (kk < 11) {
      stage_pair512(Ab, Bb, KDIM, KDIM, ks * 768 + (kk + 1) * 64, AB[cur ^ 1][0], AB[cur ^ 1][1], tid);
      asm volatile("s_waitcnt vmcnt(4)" ::: "memory");
    } else {
      asm volatile("s_waitcnt vmcnt(0)" ::: "memory");
    }
    __syncthreads();
    #pragma unroll
    for (int kb = 0; kb < 2; ++kb) {
      bf16x8 af[4], bv[2];
      #pragma unroll
      for (int mt = 0; mt < 4; ++mt) {
        int r = m0 + mt * 16 + row16;
        int c = (kb * 4 + kq) ^ (r & 7);
        af[mt] = *(const bf16x8*)&AB[cur][0][r * 64 + c * 8];
      }
      #pragma unroll
      for (int nt = 0; nt < 2; ++nt) {
        int r = n0 + nt * 16 + row16;
        int c = (kb * 4 + kq) ^ (r & 7);
        bv[nt] = *(const bf16x8*)&AB[cur][1][r * 64 + c * 8];
      }
      #pragma unroll
      for (int mt = 0; mt < 4; ++mt)
        #pragma unroll
        for (int nt = 0; nt < 2; ++nt)
          acc[mt][nt] = __builtin_amdgcn_mfma_f32_16x16x32_bf16(af[mt], bv[nt], acc[mt][nt], 0, 0, 0);
    }
    __syncthreads();
  }
  #pragma unroll
  for (int mt = 0; mt < 4; ++mt)
    #pragma unroll
    for (int nt = 0; nt < 2; ++nt)
      #pragma unroll
      for (int v4 = 0; v4 < 4; ++v4) {
        int i = i0 + m0 + mt * 16 + kq * 4 + v4;
        int j = j0 + n0 + nt * 16 + row16;
        atomicAdd(&logits[((size_t)h * LQ + i) * LQ + j], acc[mt][nt][v4]);
      }
}

// ---------------- K3: softmax over j ----------------
__global__ __launch_bounds__(256) void k_softmax(
    const float* __restrict__ logits, us* __restrict__ attn)
{
  const int tid = threadIdx.x, h = tid >> 6, l = tid & 63;
  const int i = blockIdx.x;
  const float* lrow = logits + ((size_t)h * LQ + i) * LQ;
  float x[6];
  #pragma unroll
  for (int s = 0; s < 6; ++s) x[s] = lrow[l + 64 * s];
  float mx = x[0];
  #pragma unroll
  for (int s = 1; s < 6; ++s) mx = fmaxf(mx, x[s]);
  mx = wmaxr(mx);
  float e[6], sum = 0.f;
  #pragma unroll
  for (int s = 0; s < 6; ++s) { e[s] = expf(x[s] - mx); sum += e[s]; }
  sum = wsum(sum);
  float rinv = 1.f / sum;
  #pragma unroll
  for (int s = 0; s < 6; ++s)
    attn[((size_t)h * LQ + i) * LQ + l + 64 * s] = f2bf(e[s] * rinv);
}

// ---------------- K4: o = attn @ V^T (dbuf), fused gating, E over G ----------------
__global__ __launch_bounds__(256) void k_ogemm(
    const us* __restrict__ attn, const us* __restrict__ Vw, us* __restrict__ Gw)
{
  __shared__ __attribute__((aligned(16))) us AB[2][2][8192];   // 64 KB dbuf
  const int tid = threadIdx.x, w = tid >> 6, l = tid & 63;
  const int bx = blockIdx.x;
  const int xg = bx & 7, yg = bx >> 3;        // 1152 blocks
  const int set = xg * 48 + yg / 3, i0 = (yg % 3) * 128;
  const int h = set / 96, n0 = (set % 96) * 128;
  const us* Ab = attn + (size_t)h * LQ * LQ + (size_t)i0 * LQ;
  const us* Bb = Vw + (size_t)h * KDIM * LQ + (size_t)n0 * LQ;
  f32x4 acc[4][4];
  #pragma unroll
  for (int mt = 0; mt < 4; ++mt)
    #pragma unroll
    for (int nt = 0; nt < 4; ++nt) acc[mt][nt] = (f32x4){0.f, 0.f, 0.f, 0.f};
  const int m0 = (w & 1) * 64, n0w = (w >> 1) * 64;
  const int row16 = l & 15, kq = l >> 4;
  stage_pair(Ab, Bb, LQ, LQ, 0, AB[0][0], AB[0][1], tid);
  for (int kk = 0; kk < 6; ++kk) {
    const int cur = kk & 1;
    if (kk < 5) {
      stage_pair(Ab, Bb, LQ, LQ, (kk + 1) * 64, AB[cur ^ 1][0], AB[cur ^ 1][1], tid);
      asm volatile("s_waitcnt vmcnt(8)" ::: "memory");
    } else {
      asm volatile("s_waitcnt vmcnt(0)" ::: "memory");
    }
    __syncthreads();
    #pragma unroll
    for (int kb = 0; kb < 2; ++kb) {
      bf16x8 af[4], bv[4];
      #pragma unroll
      for (int mt = 0; mt < 4; ++mt) {
        int r = m0 + mt * 16 + row16;
        int c = (kb * 4 + kq) ^ (r & 7);
        af[mt] = *(const bf16x8*)&AB[cur][0][r * 64 + c * 8];
      }
      #pragma unroll
      for (int nt = 0; nt < 4; ++nt) {
        int r = n0w + nt * 16 + row16;
        int c = (kb * 4 + kq) ^ (r & 7);
        bv[nt] = *(const bf16x8*)&AB[cur][1][r * 64 + c * 8];
      }
      #pragma unroll
      for (int mt = 0; mt < 4; ++mt)
        #pragma unroll
        for (int nt = 0; nt < 4; ++nt)
          acc[mt][nt] = __builtin_amdgcn_mfma_f32_16x16x32_bf16(af[mt], bv[nt], acc[mt][nt], 0, 0, 0);
    }
    __syncthreads();
  }
  // stage C (128x128 bf16 over buf0)
  us* C = (us*)AB;
  #pragma unroll
  for (int mt = 0; mt < 4; ++mt)
    #pragma unroll
    for (int nt = 0; nt < 4; ++nt)
      #pragma unroll
      for (int v4 = 0; v4 < 4; ++v4)
        C[(m0 + mt * 16 + kq * 4 + v4) * 128 + n0w + nt * 16 + row16] = f2bf(acc[mt][nt][v4]);
  __syncthreads();
  // gated store: E[(i*384 + k)*128 + h*32 + d] = g * o, in-place over Gw
  const int k0 = n0 >> 5;
  #pragma unroll
  for (int it = 0; it < 8; ++it) {
    int slot = tid + 256 * it;      // 0..2047
    int xr = slot >> 4, ch = slot & 15;
    bf16x8 ov = *(const bf16x8*)&C[xr * 128 + ch * 8];
    size_t eaddr = ((size_t)(i0 + xr) * LQ + k0 + (ch >> 2)) * DPAIR + h * 32 + (ch & 3) * 8;
    bf16x8 gv = *(const bf16x8*)&Gw[eaddr];
    bf16x8 ev;
    #pragma unroll
    for (int q = 0; q < 8; ++q)
      ev[q] = (short)f2bf(bf2f((us)(unsigned short)ov[q]) * bf2f((us)(unsigned short)gv[q]));
    *(bf16x8*)&Gw[eaddr] = ev;
  }
}

// ---------------- K5: out[y,x,:] = E[x,y,:] @ Wo + bo (fp32 restage + NT out) ------
__global__ __launch_bounds__(256) void k_final(
    const us* __restrict__ E, const us* __restrict__ wt,
    const float* __restrict__ bo, float* __restrict__ out)
{
  __shared__ __attribute__((aligned(16))) us A[17408];    // 34816 B
  const int tid = threadIdx.x, w = tid >> 6, l = tid & 63;
  const int y = blockIdx.x / 3, x0 = (blockIdx.x % 3) * 128;
  #pragma unroll
  for (int s4 = 0; s4 < 8; ++s4) {
    int slot = s4 * 256 + tid;
    int r = slot >> 4, c = slot & 15;
    int cg = (c & 8) | ((c & 7) ^ (r & 7));
    gl_lds16(E + ((size_t)(x0 + r) * LQ + y) * DPAIR + cg * 8, &A[slot * 8]);
  }
  asm volatile("s_waitcnt vmcnt(0)" ::: "memory");
  __syncthreads();
  const us* W = wt + 4 * 16384;       // WoT
  const int m0 = (w & 1) * 64, n0w = (w >> 1) * 64;
  const int row16 = l & 15, kq = l >> 4;
  f32x4 acc[4][4];
  #pragma unroll
  for (int mt = 0; mt < 4; ++mt)
    #pragma unroll
    for (int nt = 0; nt < 4; ++nt) acc[mt][nt] = (f32x4){0.f, 0.f, 0.f, 0.f};
  #pragma unroll
  for (int kb = 0; kb < 4; ++kb) {
    bf16x8 af[4], bv[4];
    #pragma unroll
    for (int mt = 0; mt < 4; ++mt) {
      int r = m0 + mt * 16 + row16;
      int c = (kb * 4 + kq);
      int cg = (c & 8) | ((c & 7) ^ (r & 7));
      af[mt] = *(const bf16x8*)&A[r * 128 + cg * 8];
    }
    #pragma unroll
    for (int nt = 0; nt < 4; ++nt)
      bv[nt] = *(const bf16x8*)&W[(n0w + nt * 16 + row16) * 128 + kb * 32 + kq * 8];
    #pragma unroll
    for (int mt = 0; mt < 4; ++mt)
      #pragma unroll
      for (int nt = 0; nt < 4; ++nt)
        acc[mt][nt] = __builtin_amdgcn_mfma_f32_16x16x32_bf16(af[mt], bv[nt], acc[mt][nt], 0, 0, 0);
  }
  __syncthreads();   // A dead; reuse as fp32 stage [64][136]
  float* Sf = (float*)A;
  #pragma unroll
  for (int half = 0; half < 2; ++half) {
    if ((w & 1) == half) {
      #pragma unroll
      for (int nt = 0; nt < 4; ++nt) {
        int col = n0w + nt * 16 + row16;
        float bov = bo[col];
        #pragma unroll
        for (int mt = 0; mt < 4; ++mt) {
          f32x4 vv = acc[mt][nt];
          #pragma unroll
          for (int v4 = 0; v4 < 4; ++v4)
            Sf[(mt * 16 + kq * 4 + v4) * 136 + col] = vv[v4] + bov;
        }
      }
    }
    __syncthreads();
    #pragma unroll
    for (int it = 0; it < 8; ++it) {
      int slot = it * 256 + tid;        // 0..2047
      int rw = slot >> 5, ch = slot & 31;
      f32x4 v = *(const f32x4*)&Sf[rw * 136 + ch * 4];
      __builtin_nontemporal_store(v,
        (f32x4*)&out[((size_t)y * LQ + x0 + half * 64 + rw) * DPAIR + ch * 4]);
    }
    __syncthreads();
  }
}

extern "C" void kernel_launch(void* const* d_in, const int* in_sizes, int n_in,
                              void* d_out, int out_size, void* d_ws, size_t ws_size,
                              hipStream_t stream)
{
  const float* pair = (const float*)d_in[0];
  const float* bias = (const float*)d_in[1];
  const float* lng  = (const float*)d_in[2];
  const float* lnb  = (const float*)d_in[3];
  const float* Wq   = (const float*)d_in[4];
  const float* Wk   = (const float*)d_in[5];
  const float* Wv   = (const float*)d_in[6];
  const float* Wb   = (const float*)d_in[7];
  const float* Wg   = (const float*)d_in[8];
  const float* bg   = (const float*)d_in[9];
  const float* Wo   = (const float*)d_in[10];
  const float* bo   = (const float*)d_in[11];

  char* ws = (char*)d_ws;
  us* wt     = (us*)(ws + WT_OFF);
  us* P      = (us*)(ws + P_OFF);
  us* Qw     = (us*)(ws + Q_OFF);
  us* Kw     = (us*)(ws + K_OFF);
  us* Vw     = (us*)(ws + V_OFF);
  us* Gw     = (us*)(ws + G_OFF);
  us* attn   = (us*)(ws + ATT_OFF);
  float* logits = (float*)(ws + LOG_OFF);

  k_prep<<<1472, 256, 0, stream>>>(Wq, Wk, Wv, Wg, Wo, wt, pair, lng, lnb, P);
  k_qkvg<<<4608, 256, 0, stream>>>(P, wt, bg, Qw, Kw, Vw, Gw);
  // P dead from here; logits/attn overlap its region
  (void)hipMemsetAsync(logits, 0, (size_t)4 * LQ * LQ * 4, stream);
  k_logits2<<<1728, 512, 0, stream>>>(Qw, Kw, bias, Wb, logits);
  k_softmax<<<384, 256, 0, stream>>>(logits, attn);
  k_ogemm<<<1152, 256, 0, stream>>>(attn, Vw, Gw);
  k_final<<<1152, 256, 0, stream>>>(Gw, wt, bo, (float*)d_out);
}

// Round 15
// 234.863 us; speedup vs baseline: 1.1307x; 1.0262x over previous
//
#include <hip/hip_runtime.h>
#include <math.h>

typedef unsigned short us;
typedef unsigned long long u64;
typedef short bf16x8 __attribute__((ext_vector_type(8)));
typedef short bf16x4 __attribute__((ext_vector_type(4)));
typedef float f32x4 __attribute__((ext_vector_type(4)));

#define LQ 384
#define DPAIR 128
#define KDIM 12288  // L*32

// ws byte offsets (logits/attn overlap P: P dead after k_qkvg)
#define WT_OFF   0UL
#define P_OFF    262144UL
#define LOG_OFF  262144UL
#define ATT_OFF  2621440UL
#define Q_OFF    38010880UL
#define K_OFF    75759616UL
#define V_OFF    113508352UL
#define G_OFF    151257088UL

__device__ __forceinline__ us f2bf(float x){
  unsigned u = __builtin_bit_cast(unsigned, x);
  return (us)((u + 0x7FFFu + ((u >> 16) & 1u)) >> 16);
}
__device__ __forceinline__ float bf2f(us b){
  unsigned u = ((unsigned)b) << 16;
  return __builtin_bit_cast(float, u);
}
__device__ __forceinline__ void gl_lds16(const void* g, void* l){
  __builtin_amdgcn_global_load_lds((const __attribute__((address_space(1))) unsigned*)g,
                                   (__attribute__((address_space(3))) unsigned*)l, 16, 0, 0);
}
__device__ __forceinline__ void nt_st8(us* p, bf16x8 v){
  __builtin_nontemporal_store(v, (bf16x8*)p);
}
__device__ __forceinline__ float wsum(float x){
  #pragma unroll
  for (int o = 32; o; o >>= 1) x += __shfl_xor(x, o, 64);
  return x;
}
__device__ __forceinline__ float wmaxr(float x){
  #pragma unroll
  for (int o = 32; o; o >>= 1) x = fmaxf(x, __shfl_xor(x, o, 64));
  return x;
}
// stage a 128x64 A/B pair into LDS, pre-swizzled source (256-thread blocks)
__device__ __forceinline__ void stage_pair(const us* __restrict__ Arow, const us* __restrict__ Brow,
                                           size_t strideA, size_t strideB, int koff,
                                           us* ldsA, us* ldsB, int tid)
{
  #pragma unroll
  for (int s = 0; s < 4; ++s) {
    int slot = s * 256 + tid;
    int rrow = slot >> 3, cc = slot & 7;
    int cg = cc ^ (rrow & 7);
    gl_lds16(Arow + (size_t)rrow * strideA + koff + cg * 8, &ldsA[slot * 8]);
    gl_lds16(Brow + (size_t)rrow * strideB + koff + cg * 8, &ldsB[slot * 8]);
  }
}
// same but for 512-thread blocks (2 iterations)
__device__ __forceinline__ void stage_pair512(const us* __restrict__ Arow, const us* __restrict__ Brow,
                                              size_t strideA, size_t strideB, int koff,
                                              us* ldsA, us* ldsB, int tid)
{
  #pragma unroll
  for (int s = 0; s < 2; ++s) {
    int slot = s * 512 + tid;
    int rrow = slot >> 3, cc = slot & 7;
    int cg = cc ^ (rrow & 7);
    gl_lds16(Arow + (size_t)rrow * strideA + koff + cg * 8, &ldsA[slot * 8]);
    gl_lds16(Brow + (size_t)rrow * strideB + koff + cg * 8, &ldsB[slot * 8]);
  }
}

// ---------------- K0: weight pack (blocks 0..319) + LayerNorm (blocks 320..1471) ----
__global__ __launch_bounds__(256) void k_prep(
    const float* __restrict__ Wq, const float* __restrict__ Wk,
    const float* __restrict__ Wv, const float* __restrict__ Wg,
    const float* __restrict__ Wo, us* __restrict__ wt,
    const float* __restrict__ pair, const float* __restrict__ lng,
    const float* __restrict__ lnb, us* __restrict__ P)
{
  const int bx = blockIdx.x;
  if (bx < 320) {
    int idx = bx * 256 + threadIdx.x;       // < 5*16384
    int m = idx >> 14, rr = idx & 16383, k = rr >> 7, n = rr & 127;
    const float* W; float s;
    switch (m) {
      case 0: W = Wq; s = 0.17677669529663687f; break;   // 1/sqrt(32)
      case 1: W = Wk; s = 0.05103103630798287f; break;   // 1/sqrt(384)
      case 2: W = Wv; s = 1.f; break;
      case 3: W = Wg; s = 1.f; break;
      default: W = Wo; s = 1.f; break;
    }
    wt[m * 16384 + n * 128 + k] = f2bf(W[k * 128 + n] * s);   // WT[n][k]
    return;
  }
  const int tid = threadIdx.x, w = tid >> 6, l = tid & 63;
  const int gw = (bx - 320) * 4 + w;            // 0..4607
  const int b = gw / 12, a0 = (gw % 12) * 32;
  const float2 lg = ((const float2*)lng)[l];
  const float2 lb = ((const float2*)lnb)[l];
  for (int it = 0; it < 8; ++it) {
    float2 x[4];
    #pragma unroll
    for (int rr = 0; rr < 4; ++rr) {
      int a = a0 + it * 4 + rr;
      x[rr] = ((const float2*)(pair + ((size_t)b * LQ + a) * DPAIR))[l];
    }
    #pragma unroll
    for (int rr = 0; rr < 4; ++rr) {
      int a = a0 + it * 4 + rr;
      float s = wsum(x[rr].x + x[rr].y);
      float q = wsum(x[rr].x * x[rr].x + x[rr].y * x[rr].y);
      float mu = s * (1.f / 128.f);
      float var = q * (1.f / 128.f) - mu * mu;
      float rstd = rsqrtf(var + 1e-5f);
      float y0 = (x[rr].x - mu) * rstd * lg.x + lb.x;
      float y1 = (x[rr].y - mu) * rstd * lg.y + lb.y;
      unsigned pk = (unsigned)f2bf(y0) | ((unsigned)f2bf(y1) << 16);
      ((unsigned*)(P + ((size_t)a * LQ + b) * DPAIR))[l] = pk;
    }
  }
}

// ---------------- K1: q/k/v/g projection (R11/v7: QK 4a x 32b, VG 1a x 128b, NT) ----
__global__ __launch_bounds__(256, 4) void k_qkvg(
    const us* __restrict__ P, const us* __restrict__ wt,
    const float* __restrict__ bgp,
    us* __restrict__ Qw, us* __restrict__ Kw, us* __restrict__ Vw, us* __restrict__ Gw)
{
  __shared__ __attribute__((aligned(16))) us lds[17408];   // 34816 B
  const int tid = threadIdx.x, w = tid >> 6, l = tid & 63;
  const int bx = blockIdx.x;
  const int xg = bx & 7, u = bx >> 3;                   // 4608 = 8 XCD * 576
  int type, a_base, b0; bool qk;
  if (u < 288) {          // Q/K: 1152 tiles of (4a x 32b)
    type = u & 1;
    int tq = xg * 144 + (u >> 1);                       // 0..1151
    a_base = (tq / 12) * 4; b0 = (tq % 12) * 32; qk = true;
  } else {                // V/G: 1152 tiles of (1a x 128b)
    int v = u - 288;
    type = 2 + (v & 1);
    int tv = xg * 144 + (v >> 1);
    a_base = tv / 3; b0 = (tv % 3) * 128; qk = false;
  }
  const us* W = wt + type * 16384;
  const int m0 = (w & 1) * 64, n0 = (w >> 1) * 64;
  const int row16 = l & 15, kq = l >> 4;

  // stage full A-tile once, source pre-swizzled
  #pragma unroll
  for (int s = 0; s < 8; ++s) {
    int slot = s * 256 + tid;           // 0..2047
    int r = slot >> 4, c = slot & 15;
    int cg = (c & 8) | ((c & 7) ^ (r & 7));
    size_t prow = qk ? ((size_t)(a_base + (r >> 5)) * LQ + b0 + (r & 31))
                     : ((size_t)a_base * LQ + b0 + r);
    gl_lds16(P + prow * DPAIR + cg * 8, &lds[slot * 8]);
  }
  f32x4 acc[4][4];
  #pragma unroll
  for (int mt = 0; mt < 4; ++mt)
    #pragma unroll
    for (int nt = 0; nt < 4; ++nt) acc[mt][nt] = (f32x4){0.f, 0.f, 0.f, 0.f};
  asm volatile("s_waitcnt vmcnt(0)" ::: "memory");
  __syncthreads();

  #pragma unroll
  for (int kb = 0; kb < 4; ++kb) {
    bf16x8 bv[4], af[4];
    #pragma unroll
    for (int nt = 0; nt < 4; ++nt)
      bv[nt] = *(const bf16x8*)&W[(n0 + nt * 16 + row16) * DPAIR + kb * 32 + kq * 8];
    #pragma unroll
    for (int mt = 0; mt < 4; ++mt) {
      int r = m0 + mt * 16 + row16;
      int c = kb * 4 + kq;
      int cg = (c & 8) | ((c & 7) ^ (r & 7));
      af[mt] = *(const bf16x8*)&lds[r * 128 + cg * 8];
    }
    #pragma unroll
    for (int mt = 0; mt < 4; ++mt)
      #pragma unroll
      for (int nt = 0; nt < 4; ++nt)
        acc[mt][nt] = __builtin_amdgcn_mfma_f32_16x16x32_bf16(af[mt], bv[nt], acc[mt][nt], 0, 0, 0);
  }
  __syncthreads();   // all waves done reading A before overwriting lds

  if (qk) {
    // restage C as T[h*32+bl][ag*32+cc], stride 132 -> 256B-contiguous stores
    us* T = lds;
    #pragma unroll
    for (int nt = 0; nt < 4; ++nt) {
      int n = n0 + nt * 16 + row16, h = n >> 5, cc = n & 31;
      #pragma unroll
      for (int mt = 0; mt < 4; ++mt) {
        f32x4 vv = acc[mt][nt];
        #pragma unroll
        for (int v4 = 0; v4 < 4; ++v4) {
          int r = m0 + mt * 16 + kq * 4 + v4;
          T[(h * 32 + (r & 31)) * 132 + (r >> 5) * 32 + cc] = f2bf(vv[v4]);
        }
      }
    }
    __syncthreads();
    us* dst = (type == 0) ? Qw : Kw;
    #pragma unroll
    for (int it = 0; it < 8; ++it) {
      int slot = it * 256 + tid;       // 0..2047
      int combo = slot >> 4, chunk = slot & 15;
      int h = combo >> 5, bl = combo & 31;
      bf16x8 val = *(const bf16x8*)&T[combo * 132 + chunk * 8];
      nt_st8(&dst[((size_t)h * LQ + b0 + bl) * KDIM + a_base * 32 + chunk * 8], val);
    }
  } else if (type == 2) {
    // V: stage transposed T[col(d) * 132 + row(j)], u32-packed writes
    us* T = lds;
    #pragma unroll
    for (int nt = 0; nt < 4; ++nt) {
      int col = n0 + nt * 16 + row16;
      #pragma unroll
      for (int mt = 0; mt < 4; ++mt) {
        int rowb = m0 + mt * 16 + kq * 4;
        f32x4 vv = acc[mt][nt];
        *(unsigned*)&T[col * 132 + rowb]     = (unsigned)f2bf(vv[0]) | ((unsigned)f2bf(vv[1]) << 16);
        *(unsigned*)&T[col * 132 + rowb + 2] = (unsigned)f2bf(vv[2]) | ((unsigned)f2bf(vv[3]) << 16);
      }
    }
    __syncthreads();
    #pragma unroll
    for (int it = 0; it < 8; ++it) {
      int slot = tid + 256 * it;       // 0..2047
      int d = slot >> 4, jc = slot & 15;
      bf16x4 lo = *(const bf16x4*)&T[d * 132 + jc * 8];
      bf16x4 hi = *(const bf16x4*)&T[d * 132 + jc * 8 + 4];
      bf16x8 val = __builtin_shufflevector(lo, hi, 0, 1, 2, 3, 4, 5, 6, 7);
      int h = d >> 5, dd = d & 31;
      nt_st8(&Vw[((size_t)h * KDIM + a_base * 32 + dd) * LQ + b0 + jc * 8], val);
    }
  } else {
    // G: stage row-major Cs[row * 136 + col], sigmoid fused
    us* Cs = lds;
    #pragma unroll
    for (int nt = 0; nt < 4; ++nt) {
      int col = n0 + nt * 16 + row16;
      float bgv = bgp[col];
      #pragma unroll
      for (int mt = 0; mt < 4; ++mt) {
        f32x4 vv = acc[mt][nt];
        #pragma unroll
        for (int v4 = 0; v4 < 4; ++v4) {
          float e = __expf(-(vv[v4] + bgv));
          Cs[(m0 + mt * 16 + kq * 4 + v4) * 136 + col] = f2bf(1.f / (1.f + e));
        }
      }
    }
    __syncthreads();
    #pragma unroll
    for (int it = 0; it < 8; ++it) {
      int slot = tid + 256 * it;       // 0..2047
      int row = slot >> 4, chunk = slot & 15;
      bf16x8 val = *(const bf16x8*)&Cs[row * 136 + chunk * 8];
      nt_st8(&Gw[((size_t)(a_base * LQ + b0 + row)) * DPAIR + chunk * 8], val);
    }
  }
}

// ---------------- K2: 512-thread: logits += Q K^T (blocks 0..575) + bias@Wb (576..1727)
__global__ __launch_bounds__(512) void k_logits2(
    const us* __restrict__ Qw, const us* __restrict__ Kw,
    const float* __restrict__ bias, const float* __restrict__ Wb,
    float* __restrict__ logits)
{
  __shared__ __attribute__((aligned(16))) us AB[2][2][8192];   // 64 KB dbuf
  const int tid = threadIdx.x, w = tid >> 6, l = tid & 63;
  const int bx = blockIdx.x;
  if (bx >= 576) {
    // ---- bias projection part (8 waves x 4 rows x 4 iters = 128 j-rows) ----
    float* bps = (float*)AB;     // [128][5]
    const int u2 = bx - 576;
    const int i = u2 / 3, j0 = (u2 % 3) * 128;
    const int g = l >> 4, sl = l & 15;
    const float4* Wb4 = (const float4*)Wb;
    float4 wb[8];
    #pragma unroll
    for (int e = 0; e < 8; ++e) wb[e] = Wb4[sl * 8 + e];
    #pragma unroll
    for (int it = 0; it < 4; ++it) {
      int row = it * 32 + w * 4 + g;
      int j = j0 + row;
      const float4* br = (const float4*)(bias + ((size_t)i * LQ + j) * DPAIR);
      float4 xa = br[sl * 2], xb = br[sl * 2 + 1];
      float p0 = 0.f, p1 = 0.f, p2 = 0.f, p3 = 0.f;
      #pragma unroll
      for (int e = 0; e < 4; ++e) {
        float xe = ((const float*)&xa)[e];
        p0 += xe * wb[e].x; p1 += xe * wb[e].y; p2 += xe * wb[e].z; p3 += xe * wb[e].w;
        float xf = ((const float*)&xb)[e];
        p0 += xf * wb[4 + e].x; p1 += xf * wb[4 + e].y; p2 += xf * wb[4 + e].z; p3 += xf * wb[4 + e].w;
      }
      #pragma unroll
      for (int o = 1; o < 16; o <<= 1) {
        p0 += __shfl_xor(p0, o, 64);
        p1 += __shfl_xor(p1, o, 64);
        p2 += __shfl_xor(p2, o, 64);
        p3 += __shfl_xor(p3, o, 64);
      }
      if (sl == 0) {
        bps[row * 5 + 0] = p0; bps[row * 5 + 1] = p1; bps[row * 5 + 2] = p2; bps[row * 5 + 3] = p3;
      }
    }
    __syncthreads();
    {
      int h = tid >> 7, jj = tid & 127;
      atomicAdd(&logits[((size_t)h * LQ + i) * LQ + j0 + jj], bps[jj * 5 + h]);
    }
    return;
  }
  // ---- QK^T GEMM (K-split 16, dbuf counted-vmcnt, 8 waves 2x4) ----
  const int xg = bx & 7, yg = bx >> 3;        // 576 blocks: yg 0..71
  const int set = xg * 24 + yg / 3, j0 = (yg % 3) * 128;
  const int h = set / 48, rem = set % 48, i0 = (rem / 16) * 128, ks = rem % 16;
  const us* Ab = Qw + (size_t)h * LQ * KDIM + (size_t)i0 * KDIM;
  const us* Bb = Kw + (size_t)h * LQ * KDIM + (size_t)j0 * KDIM;
  f32x4 acc[4][2];
  #pragma unroll
  for (int mt = 0; mt < 4; ++mt) { acc[mt][0] = (f32x4){0,0,0,0}; acc[mt][1] = (f32x4){0,0,0,0}; }
  const int m0 = (w & 1) * 64, n0 = (w >> 1) * 32;
  const int row16 = l & 15, kq = l >> 4;
  stage_pair512(Ab, Bb, KDIM, KDIM, ks * 768, AB[0][0], AB[0][1], tid);
  for (int kk = 0; kk < 12; ++kk) {
    const int cur = kk & 1;
    if (kk < 11) {
      stage_pair512(Ab, Bb, KDIM, KDIM, ks * 768 + (kk + 1) * 64, AB[cur ^ 1][0], AB[cur ^ 1][1], tid);
      asm volatile("s_waitcnt vmcnt(4)" ::: "memory");
    } else {
      asm volatile("s_waitcnt vmcnt(0)" ::: "memory");
    }
    __syncthreads();
    #pragma unroll
    for (int kb = 0; kb < 2; ++kb) {
      bf16x8 af[4], bv[2];
      #pragma unroll
      for (int mt = 0; mt < 4; ++mt) {
        int r = m0 + mt * 16 + row16;
        int c = (kb * 4 + kq) ^ (r & 7);
        af[mt] = *(const bf16x8*)&AB[cur][0][r * 64 + c * 8];
      }
      #pragma unroll
      for (int nt = 0; nt < 2; ++nt) {
        int r = n0 + nt * 16 + row16;
        int c = (kb * 4 + kq) ^ (r & 7);
        bv[nt] = *(const bf16x8*)&AB[cur][1][r * 64 + c * 8];
      }
      #pragma unroll
      for (int mt = 0; mt < 4; ++mt)
        #pragma unroll
        for (int nt = 0; nt < 2; ++nt)
          acc[mt][nt] = __builtin_amdgcn_mfma_f32_16x16x32_bf16(af[mt], bv[nt], acc[mt][nt], 0, 0, 0);
    }
    __syncthreads();
  }
  #pragma unroll
  for (int mt = 0; mt < 4; ++mt)
    #pragma unroll
    for (int nt = 0; nt < 2; ++nt)
      #pragma unroll
      for (int v4 = 0; v4 < 4; ++v4) {
        int i = i0 + m0 + mt * 16 + kq * 4 + v4;
        int j = j0 + n0 + nt * 16 + row16;
        atomicAdd(&logits[((size_t)h * LQ + i) * LQ + j], acc[mt][nt][v4]);
      }
}

// ---------------- K3: softmax over j ----------------
__global__ __launch_bounds__(256) void k_softmax(
    const float* __restrict__ logits, us* __restrict__ attn)
{
  const int tid = threadIdx.x, h = tid >> 6, l = tid & 63;
  const int i = blockIdx.x;
  const float* lrow = logits + ((size_t)h * LQ + i) * LQ;
  float x[6];
  #pragma unroll
  for (int s = 0; s < 6; ++s) x[s] = lrow[l + 64 * s];
  float mx = x[0];
  #pragma unroll
  for (int s = 1; s < 6; ++s) mx = fmaxf(mx, x[s]);
  mx = wmaxr(mx);
  float e[6], sum = 0.f;
  #pragma unroll
  for (int s = 0; s < 6; ++s) { e[s] = expf(x[s] - mx); sum += e[s]; }
  sum = wsum(sum);
  float rinv = 1.f / sum;
  #pragma unroll
  for (int s = 0; s < 6; ++s)
    attn[((size_t)h * LQ + i) * LQ + l + 64 * s] = f2bf(e[s] * rinv);
}

// ---------------- K4: 512-thread o = attn @ V^T (dbuf, 8 waves 2x4), fused gating ----
__global__ __launch_bounds__(512) void k_ogemm(
    const us* __restrict__ attn, const us* __restrict__ Vw, us* __restrict__ Gw)
{
  __shared__ __attribute__((aligned(16))) us AB[2][2][8192];   // 64 KB dbuf
  const int tid = threadIdx.x, w = tid >> 6, l = tid & 63;
  const int bx = blockIdx.x;
  const int xg = bx & 7, yg = bx >> 3;        // 1152 blocks
  const int set = xg * 48 + yg / 3, i0 = (yg % 3) * 128;
  const int h = set / 96, n0 = (set % 96) * 128;
  const us* Ab = attn + (size_t)h * LQ * LQ + (size_t)i0 * LQ;
  const us* Bb = Vw + (size_t)h * KDIM * LQ + (size_t)n0 * LQ;
  f32x4 acc[4][2];
  #pragma unroll
  for (int mt = 0; mt < 4; ++mt) { acc[mt][0] = (f32x4){0,0,0,0}; acc[mt][1] = (f32x4){0,0,0,0}; }
  const int m0 = (w & 1) * 64, n0w = (w >> 1) * 32;
  const int row16 = l & 15, kq = l >> 4;
  stage_pair512(Ab, Bb, LQ, LQ, 0, AB[0][0], AB[0][1], tid);
  for (int kk = 0; kk < 6; ++kk) {
    const int cur = kk & 1;
    if (kk < 5) {
      stage_pair512(Ab, Bb, LQ, LQ, (kk + 1) * 64, AB[cur ^ 1][0], AB[cur ^ 1][1], tid);
      asm volatile("s_waitcnt vmcnt(4)" ::: "memory");
    } else {
      asm volatile("s_waitcnt vmcnt(0)" ::: "memory");
    }
    __syncthreads();
    #pragma unroll
    for (int kb = 0; kb < 2; ++kb) {
      bf16x8 af[4], bv[2];
      #pragma unroll
      for (int mt = 0; mt < 4; ++mt) {
        int r = m0 + mt * 16 + row16;
        int c = (kb * 4 + kq) ^ (r & 7);
        af[mt] = *(const bf16x8*)&AB[cur][0][r * 64 + c * 8];
      }
      #pragma unroll
      for (int nt = 0; nt < 2; ++nt) {
        int r = n0w + nt * 16 + row16;
        int c = (kb * 4 + kq) ^ (r & 7);
        bv[nt] = *(const bf16x8*)&AB[cur][1][r * 64 + c * 8];
      }
      #pragma unroll
      for (int mt = 0; mt < 4; ++mt)
        #pragma unroll
        for (int nt = 0; nt < 2; ++nt)
          acc[mt][nt] = __builtin_amdgcn_mfma_f32_16x16x32_bf16(af[mt], bv[nt], acc[mt][nt], 0, 0, 0);
    }
    __syncthreads();
  }
  // stage C (128x128 bf16 over buf0)
  us* C = (us*)AB;
  #pragma unroll
  for (int mt = 0; mt < 4; ++mt)
    #pragma unroll
    for (int nt = 0; nt < 2; ++nt)
      #pragma unroll
      for (int v4 = 0; v4 < 4; ++v4)
        C[(m0 + mt * 16 + kq * 4 + v4) * 128 + n0w + nt * 16 + row16] = f2bf(acc[mt][nt][v4]);
  __syncthreads();
  // gated store: E[(i*384 + k)*128 + h*32 + d] = g * o, in-place over Gw
  const int k0 = n0 >> 5;
  #pragma unroll
  for (int it = 0; it < 4; ++it) {
    int slot = tid + 512 * it;      // 0..2047
    int xr = slot >> 4, ch = slot & 15;
    bf16x8 ov = *(const bf16x8*)&C[xr * 128 + ch * 8];
    size_t eaddr = ((size_t)(i0 + xr) * LQ + k0 + (ch >> 2)) * DPAIR + h * 32 + (ch & 3) * 8;
    bf16x8 gv = *(const bf16x8*)&Gw[eaddr];
    bf16x8 ev;
    #pragma unroll
    for (int q = 0; q < 8; ++q)
      ev[q] = (short)f2bf(bf2f((us)(unsigned short)ov[q]) * bf2f((us)(unsigned short)gv[q]));
    *(bf16x8*)&Gw[eaddr] = ev;
  }
}

// ---------------- K5: out[y,x,:] = E[x,y,:] @ Wo + bo (fp32 restage + NT out) ------
__global__ __launch_bounds__(256) void k_final(
    const us* __restrict__ E, const us* __restrict__ wt,
    const float* __restrict__ bo, float* __restrict__ out)
{
  __shared__ __attribute__((aligned(16))) us A[17408];    // 34816 B
  const int tid = threadIdx.x, w = tid >> 6, l = tid & 63;
  const int y = blockIdx.x / 3, x0 = (blockIdx.x % 3) * 128;
  #pragma unroll
  for (int s4 = 0; s4 < 8; ++s4) {
    int slot = s4 * 256 + tid;
    int r = slot >> 4, c = slot & 15;
    int cg = (c & 8) | ((c & 7) ^ (r & 7));
    gl_lds16(E + ((size_t)(x0 + r) * LQ + y) * DPAIR + cg * 8, &A[slot * 8]);
  }
  asm volatile("s_waitcnt vmcnt(0)" ::: "memory");
  __syncthreads();
  const us* W = wt + 4 * 16384;       // WoT
  const int m0 = (w & 1) * 64, n0w = (w >> 1) * 64;
  const int row16 = l & 15, kq = l >> 4;
  f32x4 acc[4][4];
  #pragma unroll
  for (int mt = 0; mt < 4; ++mt)
    #pragma unroll
    for (int nt = 0; nt < 4; ++nt) acc[mt][nt] = (f32x4){0.f, 0.f, 0.f, 0.f};
  #pragma unroll
  for (int kb = 0; kb < 4; ++kb) {
    bf16x8 af[4], bv[4];
    #pragma unroll
    for (int mt = 0; mt < 4; ++mt) {
      int r = m0 + mt * 16 + row16;
      int c = (kb * 4 + kq);
      int cg = (c & 8) | ((c & 7) ^ (r & 7));
      af[mt] = *(const bf16x8*)&A[r * 128 + cg * 8];
    }
    #pragma unroll
    for (int nt = 0; nt < 4; ++nt)
      bv[nt] = *(const bf16x8*)&W[(n0w + nt * 16 + row16) * 128 + kb * 32 + kq * 8];
    #pragma unroll
    for (int mt = 0; mt < 4; ++mt)
      #pragma unroll
      for (int nt = 0; nt < 4; ++nt)
        acc[mt][nt] = __builtin_amdgcn_mfma_f32_16x16x32_bf16(af[mt], bv[nt], acc[mt][nt], 0, 0, 0);
  }
  __syncthreads();   // A dead; reuse as fp32 stage [64][136]
  float* Sf = (float*)A;
  #pragma unroll
  for (int half = 0; half < 2; ++half) {
    if ((w & 1) == half) {
      #pragma unroll
      for (int nt = 0; nt < 4; ++nt) {
        int col = n0w + nt * 16 + row16;
        float bov = bo[col];
        #pragma unroll
        for (int mt = 0; mt < 4; ++mt) {
          f32x4 vv = acc[mt][nt];
          #pragma unroll
          for (int v4 = 0; v4 < 4; ++v4)
            Sf[(mt * 16 + kq * 4 + v4) * 136 + col] = vv[v4] + bov;
        }
      }
    }
    __syncthreads();
    #pragma unroll
    for (int it = 0; it < 8; ++it) {
      int slot = it * 256 + tid;        // 0..2047
      int rw = slot >> 5, ch = slot & 31;
      f32x4 v = *(const f32x4*)&Sf[rw * 136 + ch * 4];
      __builtin_nontemporal_store(v,
        (f32x4*)&out[((size_t)y * LQ + x0 + half * 64 + rw) * DPAIR + ch * 4]);
    }
    __syncthreads();
  }
}

extern "C" void kernel_launch(void* const* d_in, const int* in_sizes, int n_in,
                              void* d_out, int out_size, void* d_ws, size_t ws_size,
                              hipStream_t stream)
{
  const float* pair = (const float*)d_in[0];
  const float* bias = (const float*)d_in[1];
  const float* lng  = (const float*)d_in[2];
  const float* lnb  = (const float*)d_in[3];
  const float* Wq   = (const float*)d_in[4];
  const float* Wk   = (const float*)d_in[5];
  const float* Wv   = (const float*)d_in[6];
  const float* Wb   = (const float*)d_in[7];
  const float* Wg   = (const float*)d_in[8];
  const float* bg   = (const float*)d_in[9];
  const float* Wo   = (const float*)d_in[10];
  const float* bo   = (const float*)d_in[11];

  char* ws = (char*)d_ws;
  us* wt     = (us*)(ws + WT_OFF);
  us* P      = (us*)(ws + P_OFF);
  us* Qw     = (us*)(ws + Q_OFF);
  us* Kw     = (us*)(ws + K_OFF);
  us* Vw     = (us*)(ws + V_OFF);
  us* Gw     = (us*)(ws + G_OFF);
  us* attn   = (us*)(ws + ATT_OFF);
  float* logits = (float*)(ws + LOG_OFF);

  k_prep<<<1472, 256, 0, stream>>>(Wq, Wk, Wv, Wg, Wo, wt, pair, lng, lnb, P);
  k_qkvg<<<4608, 256, 0, stream>>>(P, wt, bg, Qw, Kw, Vw, Gw);
  // P dead from here; logits/attn overlap its region
  (void)hipMemsetAsync(logits, 0, (size_t)4 * LQ * LQ * 4, stream);
  k_logits2<<<1728, 512, 0, stream>>>(Qw, Kw, bias, Wb, logits);
  k_softmax<<<384, 256, 0, stream>>>(logits, attn);
  k_ogemm<<<1152, 512, 0, stream>>>(attn, Vw, Gw);
  k_final<<<1152, 256, 0, stream>>>(Gw, wt, bo, (float*)d_out);
}